// Round 13
// baseline (5468.922 us; speedup 1.0000x reference)
//
#include <hip/hip_runtime.h>
#include <hip/hip_cooperative_groups.h>

namespace cg = cooperative_groups;

#define NB 8192
#define NH 512
#define NZ 128
#define NIN 128
#define NN 512
#define NRW 16
#define NG 2048   // 4*NH

typedef _Float16 f16;
typedef _Float16 f16x8 __attribute__((ext_vector_type(8)));
typedef float f32x4 __attribute__((ext_vector_type(4)));

__device__ __forceinline__ float sigm(float x) { return 1.0f / (1.0f + expf(-x)); }

// gate-interleaved column permutation: stored col c <- original col oc(c)
__device__ __forceinline__ int oc_of(int c)
{
    return (((c >> 4) & 3) << 9) + ((c >> 6) << 4) + (c & 15);
}
__device__ __forceinline__ int cperm(int j)
{
    return (j & 15) | (((j >> 4) & 31) << 6) | (((j >> 9) & 3) << 4);
}

// Bijective XCD-chunk swizzle on a linear tile index (nwg % 8 == 0).
__device__ __forceinline__ int swz_lin(int lin, int nwg)
{
    return (lin & 7) * (nwg >> 3) + (lin >> 3);
}

// blockIdx-based variant for the prep kernels.
__device__ __forceinline__ void swz_xcd(int& bx, int& by)
{
    const int gx = gridDim.x;
    const int nwg = gx * gridDim.y;
    int lin = by * gx + bx;
    lin = swz_lin(lin, nwg);
    const int sh = 31 - __clz(gx);
    bx = lin & (gx - 1);
    by = lin >> sh;
}

// ---------------- async 16B global->LDS ----------------
__device__ __forceinline__ void gload16(const f16* g, f16* l)
{
    __builtin_amdgcn_global_load_lds(
        (const __attribute__((address_space(1))) void*)g,
        (__attribute__((address_space(3))) void*)l, 16, 0, 0);
}

__device__ __forceinline__ int swz4(int row) { return (row & 3) ^ ((row >> 2) & 3); }

// Stage one 128x32 f16 A-tile (8KB): linear LDS dest + inverse-swizzled global src.
__device__ __forceinline__ void stage_tile(f16* tilebase, const f16* src,
                                           int rowbase, int kb, int wid, int lane)
{
#pragma unroll
    for (int q = 0; q < 2; ++q) {
        const int iw = wid * 2 + q;
        const int chunk = (iw << 6) | lane;
        const int row = chunk >> 2;
        const int p = (chunk & 3) ^ swz4(row);
        const f16* g = src + (size_t)(rowbase + row) * NH + kb + (p << 3);
        gload16(g, tilebase + (iw << 9));
    }
}

__device__ __forceinline__ f16x8 frag(const f16* tile, int row, int sl)
{
    return *(const f16x8*)(tile + row * 32 + ((sl ^ swz4(row)) << 3));
}

__device__ __forceinline__ void readA(f16x8 (&a)[4], const f16* sbuf, int wr, int r16, int sl)
{
#pragma unroll
    for (int f = 0; f < 4; ++f) a[f] = frag(sbuf, wr + f * 16 + r16, sl);
}

// Packed-B frag load: per (nblk,kt) an 8KB chunk (4096 f16).
// group g = wc2*256 + f*64 + lane  ->  element offset wc2*2048 + f*512 + lane*8.
__device__ __forceinline__ void loadBfr(f16x8 (&d)[4], const f16* p, size_t base)
{
#pragma unroll
    for (int f = 0; f < 4; ++f) d[f] = *(const f16x8*)(p + base + f * 512);
}

__device__ __forceinline__ f32x4 MM(const f16x8 a, const f16x8 b, f32x4 c)
{
    return __builtin_amdgcn_mfma_f32_16x16x32_f16(a, b, c, 0, 0, 0);
}

// ---------------- single-acc split core: acc = (Ahi+Alo)(Bhi+Blo) [al*bl dropped] ----------------
template<int SPLIT>
__device__ __forceinline__ void core3(const f16* Ahi, const f16* Alo,
                                      const f16* Bph, const f16* Bpl,
                                      f16* s0h, f16* s0l, f16* s1h, f16* s1l,
                                      int bm, int bnblk, int wid, int lane, int wr, int wc2,
                                      f32x4 (&acc)[4][4])
{
    const int r16 = lane & 15, sl = lane >> 4;
    const size_t bwoff = (size_t)(wc2 << 11) + lane * 8;
    f16x8 bAh[4], bAl[4], bBh[4], bBl[4];

    stage_tile(s0h, Ahi, bm, 0, wid, lane);
    if (SPLIT) stage_tile(s0l, Alo, bm, 0, wid, lane);
    loadBfr(bAh, Bph, (((size_t)bnblk << 4) << 12) + bwoff);
    if (SPLIT) loadBfr(bAl, Bpl, (((size_t)bnblk << 4) << 12) + bwoff);

#pragma unroll 1
    for (int kt = 0; kt < 16; kt += 2) {
        __syncthreads();
        {
            const int kn = kt + 1;
            stage_tile(s1h, Ahi, bm, kn << 5, wid, lane);
            if (SPLIT) stage_tile(s1l, Alo, bm, kn << 5, wid, lane);
            loadBfr(bBh, Bph, ((((size_t)bnblk << 4) + kn) << 12) + bwoff);
            if (SPLIT) loadBfr(bBl, Bpl, ((((size_t)bnblk << 4) + kn) << 12) + bwoff);
        }
        f16x8 ah[4], al[4];
        readA(ah, s0h, wr, r16, sl);
        if (SPLIT) readA(al, s0l, wr, r16, sl);
        __builtin_amdgcn_s_setprio(1);
#pragma unroll
        for (int i = 0; i < 4; ++i)
#pragma unroll
            for (int j = 0; j < 4; ++j) {
                acc[i][j] = MM(ah[i], bAh[j], acc[i][j]);
                if (SPLIT) {
                    acc[i][j] = MM(al[i], bAh[j], acc[i][j]);
                    acc[i][j] = MM(ah[i], bAl[j], acc[i][j]);
                }
            }
        __builtin_amdgcn_s_setprio(0);
        __syncthreads();
        if (kt + 2 < 16) {
            const int kn = kt + 2;
            stage_tile(s0h, Ahi, bm, kn << 5, wid, lane);
            if (SPLIT) stage_tile(s0l, Alo, bm, kn << 5, wid, lane);
            loadBfr(bAh, Bph, ((((size_t)bnblk << 4) + kn) << 12) + bwoff);
            if (SPLIT) loadBfr(bAl, Bpl, ((((size_t)bnblk << 4) + kn) << 12) + bwoff);
        }
        readA(ah, s1h, wr, r16, sl);
        if (SPLIT) readA(al, s1l, wr, r16, sl);
        __builtin_amdgcn_s_setprio(1);
#pragma unroll
        for (int i = 0; i < 4; ++i)
#pragma unroll
            for (int j = 0; j < 4; ++j) {
                acc[i][j] = MM(ah[i], bBh[j], acc[i][j]);
                if (SPLIT) {
                    acc[i][j] = MM(al[i], bBh[j], acc[i][j]);
                    acc[i][j] = MM(ah[i], bBl[j], acc[i][j]);
                }
            }
        __builtin_amdgcn_s_setprio(0);
    }
}

// ---------------- shared job helpers ----------------
__device__ __forceinline__ void gather_win(int* winlds, const float2* part, int bm)
{
    const int tid = threadIdx.x;
    if (tid < 128) {
        const float2* p = part + (size_t)(bm + tid) * 8;
        float best = -INFINITY;
        int bi = 0x7fffffff;
#pragma unroll
        for (int q = 0; q < 8; ++q) {
            const float2 pv = p[q];
            if (pv.x > best || (pv.x == best && (int)pv.y < bi)) { best = pv.x; bi = (int)pv.y; }
        }
        winlds[tid] = bi;
    }
}

__device__ __forceinline__ void write_onehot(float* out0, int bm, int bx, int t_out,
                                             const int* winlds)
{
    const int tid = threadIdx.x;
    const int rr = tid >> 1;
    const int cs = (bx << 5) + ((tid & 1) << 4);
    const int win = winlds[rr];
    float* orow = out0 + ((size_t)(bm + rr) * NRW + t_out) * NN + cs;
#pragma unroll
    for (int e = 0; e < 16; e += 4) {
        const int c0 = cs + e;
        *(float4*)(orow + e) = make_float4(c0 == win, c0 + 1 == win, c0 + 2 == win, c0 + 3 == win);
    }
}

// ---------------- job: loop-1 gate tile ----------------
template<int HAS_PART>
__device__ __forceinline__ void job_gate1(f16 (*s)[4096], int* winlds, int bx, int by,
                                          const f16* a1hi, const f16* a1lo,
                                          const f16* Wlp_hi, const f16* Wlp_lo,
                                          const float* blp, const float* gdown,
                                          const float2* part,
                                          float* out0, int t_out,
                                          float* c1, f16* o1hi, f16* o1lo)
{
    const int bm = by << 7;
    const int tid = threadIdx.x;
    const int wid = tid >> 6, lane = tid & 63;
    const int wr = ((wid >> 1) & 1) << 6;
    const int wc2 = wid & 1;
    __syncthreads();                       // protect winlds/LDS from previous job
    if (HAS_PART) gather_win(winlds, part, bm);

    f32x4 acc[4][4];
#pragma unroll
    for (int i = 0; i < 4; ++i)
#pragma unroll
        for (int j = 0; j < 4; ++j) acc[i][j] = (f32x4)(0.0f);

    core3<1>(a1hi, a1lo, Wlp_hi, Wlp_lo, s[0], s[1], s[2], s[3], bm, bx, wid, lane, wr, wc2, acc);

    const int m = lane & 15, rg = lane >> 4;
    const int colb = (bx << 7) + (wc2 << 6);
    const int jj = ((colb >> 6) << 4) + m;
    float bi4[4];
#pragma unroll
    for (int g = 0; g < 4; ++g) bi4[g] = blp[colb + g * 16 + m];

#pragma unroll
    for (int i = 0; i < 4; ++i) {
#pragma unroll
        for (int r = 0; r < 4; ++r) {
            const int row = bm + wr + i * 16 + rg * 4 + r;
            float ex[4] = {0.f, 0.f, 0.f, 0.f};
            if (HAS_PART) {
                const float* exr = gdown + (size_t)winlds[row - bm] * NG;
#pragma unroll
                for (int g = 0; g < 4; ++g) ex[g] = exr[colb + g * 16 + m];
            }
            const float ig = acc[i][0][r] + bi4[0] + ex[0];
            const float gg = acc[i][1][r] + bi4[1] + ex[1];
            const float fg = acc[i][2][r] + bi4[2] + ex[2];
            const float og = acc[i][3][r] + bi4[3] + ex[3];
            const size_t cidx = (size_t)row * NH + jj;
            const float cx = c1[cidx];
            const float cy = cx * sigm(fg + 1.0f) + sigm(ig) * tanhf(gg);
            const float hy = sigm(og) * tanhf(cy);
            c1[cidx] = cy;
            const f16 a = (f16)hy;
            o1hi[cidx] = a;
            o1lo[cidx] = (f16)(hy - (float)a);
        }
    }
    if (HAS_PART) write_onehot(out0, bm, bx, t_out, winlds);
}

// ---------------- job: loop-2 gate tile (1-pass f16 + rowdot) ----------------
template<int WRITE_OUT0>
__device__ __forceinline__ void job_gate2(f16 (*s)[4096], int* winlds, int bx, int by,
                                          const f16* a2hi, const f16* Wlp_hi,
                                          const float* blp, const float* gdownl,
                                          const float2* part,
                                          float* out0, int t_out,
                                          float* c2, f16* o2hi,
                                          const float* Woutl, float* out1, int t2)
{
    const int bm = by << 7;
    const int tid = threadIdx.x;
    const int wid = tid >> 6, lane = tid & 63;
    const int wr = ((wid >> 1) & 1) << 6;
    const int wc2 = wid & 1;
    __syncthreads();
    gather_win(winlds, part, bm);

    f32x4 acc[4][4];
#pragma unroll
    for (int i = 0; i < 4; ++i)
#pragma unroll
        for (int j = 0; j < 4; ++j) acc[i][j] = (f32x4)(0.0f);

    core3<0>(a2hi, nullptr, Wlp_hi, nullptr, s[0], nullptr, s[1], nullptr,
             bm, bx, wid, lane, wr, wc2, acc);

    const int m = lane & 15, rg = lane >> 4;
    const int colb = (bx << 7) + (wc2 << 6);
    const int jj = ((colb >> 6) << 4) + m;
    const float wout = Woutl[jj];
    float bi4[4];
#pragma unroll
    for (int g = 0; g < 4; ++g) bi4[g] = blp[colb + g * 16 + m];

#pragma unroll
    for (int i = 0; i < 4; ++i) {
#pragma unroll
        for (int r = 0; r < 4; ++r) {
            const int row = bm + wr + i * 16 + rg * 4 + r;
            const float* exr = gdownl + (size_t)winlds[row - bm] * NG;
            float ex[4];
#pragma unroll
            for (int g = 0; g < 4; ++g) ex[g] = exr[colb + g * 16 + m];
            const float ig = acc[i][0][r] + bi4[0] + ex[0];
            const float gg = acc[i][1][r] + bi4[1] + ex[1];
            const float fg = acc[i][2][r] + bi4[2] + ex[2];
            const float og = acc[i][3][r] + bi4[3] + ex[3];
            const size_t cidx = (size_t)row * NH + jj;
            const float cx = c2[cidx];
            const float cy = cx * sigm(fg + 1.0f) + sigm(ig) * tanhf(gg);
            const float hy = sigm(og) * tanhf(cy);
            c2[cidx] = cy;
            o2hi[cidx] = (f16)hy;
            float pt = hy * wout;
#pragma unroll
            for (int msk = 1; msk < 16; msk <<= 1) pt += __shfl_xor(pt, msk);
            if (m == 0) atomicAdd(&out1[(size_t)row * NRW + t2], pt);
        }
    }
    if (WRITE_OUT0) write_onehot(out0, bm, bx, t_out, winlds);
}

// ---------------- job: logits GEMM + gumbel-argmax partials ----------------
__device__ __forceinline__ void job_logits(f16 (*s)[4096], int bx, int by,
                                           const f16* Ahi, const f16* Alo,
                                           const f16* Bph, const f16* Bpl,
                                           const float* bias, const float* gu,
                                           float2* part, int t)
{
    const int bm = by << 7;
    const int tid = threadIdx.x;
    const int wid = tid >> 6, lane = tid & 63;
    const int wr = ((wid >> 1) & 1) << 6;
    const int wc2 = wid & 1;
    __syncthreads();

    f32x4 acc[4][4];
#pragma unroll
    for (int i = 0; i < 4; ++i)
#pragma unroll
        for (int j = 0; j < 4; ++j) acc[i][j] = (f32x4)(0.0f);

    core3<1>(Ahi, Alo, Bph, Bpl, s[0], s[1], s[2], s[3], bm, bx, wid, lane, wr, wc2, acc);

    const int r16 = lane & 15, rg = lane >> 4;
    const int cb = (bx << 1) + wc2;
    float bi[4];
#pragma unroll
    for (int j = 0; j < 4; ++j) bi[j] = bias[(bx << 7) + (wc2 << 6) + j * 16 + r16];

#pragma unroll
    for (int i = 0; i < 4; ++i) {
#pragma unroll
        for (int r = 0; r < 4; ++r) {
            const int row = bm + wr + i * 16 + rg * 4 + r;
            const float* urow = gu + ((size_t)t * NB + row) * NN;
            float best = -INFINITY;
            int bidx = 0x7fffffff;
#pragma unroll
            for (int j = 0; j < 4; ++j) {
                const int col = (bx << 7) + (wc2 << 6) + j * 16 + r16;
                const float u = urow[col];
                const float g = -logf(-logf(u + 1e-20f) + 1e-20f);
                const float v = acc[i][j][r] + bi[j] + g;
                if (v > best || (v == best && col < bidx)) { best = v; bidx = col; }
            }
#pragma unroll
            for (int msk = 1; msk < 16; msk <<= 1) {
                const float ov = __shfl_xor(best, msk);
                const int oi = __shfl_xor(bidx, msk);
                if (ov > best || (ov == best && oi < bidx)) { best = ov; bidx = oi; }
            }
            if (r16 == 0) part[(size_t)row * 8 + cb] = make_float2(best, (float)bidx);
        }
    }
}

// ---------------- persistent cooperative main loop ----------------
__global__ __launch_bounds__(256, 2)
void persist_loop(const f16* __restrict__ Wlp_hi, const f16* __restrict__ Wlp_lo,
                  const f16* __restrict__ Wup_hi, const f16* __restrict__ Wup_lo,
                  const float* __restrict__ blp, const float* __restrict__ bup,
                  const float* __restrict__ gdown, const float* __restrict__ gdownl,
                  const float* __restrict__ gu, const float* __restrict__ Woutl,
                  float2* __restrict__ part, float* __restrict__ out0,
                  float* __restrict__ out1,
                  float* __restrict__ c1, float* __restrict__ c2,
                  f16* h1hi0, f16* h1lo0, f16* h1hi1, f16* h1lo1,
                  f16* h2hi0, f16* h2hi1)
{
    cg::grid_group grid = cg::this_grid();
    __shared__ f16 s[4][4096];
    __shared__ int winlds[128];
    f16* h1hi[2] = {h1hi0, h1hi1};
    f16* h1lo[2] = {h1lo0, h1lo1};
    f16* h2hi[2] = {h2hi0, h2hi1};

    for (int t = 0; t <= NRW; ++t) {
        const int nL1 = (t < NRW) ? 1024 : 0;
        const int nTot = nL1 + ((t >= 1) ? 1024 : 0);
        for (int job = blockIdx.x; job < nTot; job += gridDim.x) {
            const bool isL1 = job < nL1;
            const int tile = isL1 ? job : (job - nL1);
            const int lin = swz_lin(tile, 1024);
            const int bx = lin & 15, by = lin >> 4;
            if (isL1) {
                if (t == 0)
                    job_gate1<0>(s, winlds, bx, by, h1hi[0], h1lo[0], Wlp_hi, Wlp_lo,
                                 blp, gdown, nullptr, out0, 0, c1, h1hi[1], h1lo[1]);
                else
                    job_gate1<1>(s, winlds, bx, by, h1hi[t & 1], h1lo[t & 1], Wlp_hi, Wlp_lo,
                                 blp, gdown, part, out0, t - 1,
                                 c1, h1hi[(t + 1) & 1], h1lo[(t + 1) & 1]);
            } else {
                const int s2 = t - 1;
                if (t == NRW)
                    job_gate2<1>(s, winlds, bx, by, h2hi[s2 & 1], Wlp_hi, blp, gdownl, part,
                                 out0, NRW - 1, c2, h2hi[(s2 + 1) & 1], Woutl, out1, s2);
                else
                    job_gate2<0>(s, winlds, bx, by, h2hi[s2 & 1], Wlp_hi, blp, gdownl, part,
                                 out0, 0, c2, h2hi[(s2 + 1) & 1], Woutl, out1, s2);
            }
        }
        grid.sync();
        if (t == NRW) break;
        for (int job = blockIdx.x; job < 256; job += gridDim.x) {
            const int lin = swz_lin(job, 256);
            const int bx = lin & 3, by = lin >> 2;
            job_logits(s, bx, by, h1hi[(t + 1) & 1], h1lo[(t + 1) & 1],
                       Wup_hi, Wup_lo, bup, gu, part, t);
        }
        grid.sync();
    }
}

// ---------------- fallback wrapper kernels (round-12 structure) ----------------
template<int DO_L1, int DO_L2>
__global__ __launch_bounds__(256, 2)
void fused_gate_fb(const f16* a1hi, const f16* a1lo, const f16* a2hi,
                   const f16* Wlp_hi, const f16* Wlp_lo, const float* blp,
                   const float* gdown, const float* gdownl,
                   const float2* part, float* out0, int t_out,
                   float* c1, f16* o1hi, f16* o1lo,
                   float* c2, f16* o2hi,
                   const float* Woutl, float* out1, int t2)
{
    __shared__ f16 s[4][4096];
    __shared__ int winlds[128];
    int lin = blockIdx.y * 16 + blockIdx.x;
    lin = swz_lin(lin, 1024);
    const int bx = lin & 15, by = lin >> 4;
    const bool isL1 = DO_L1 && (!DO_L2 || blockIdx.z == 0);
    if (isL1) {
        if (part)
            job_gate1<1>(s, winlds, bx, by, a1hi, a1lo, Wlp_hi, Wlp_lo, blp, gdown,
                         part, out0, t_out, c1, o1hi, o1lo);
        else
            job_gate1<0>(s, winlds, bx, by, a1hi, a1lo, Wlp_hi, Wlp_lo, blp, gdown,
                         nullptr, out0, 0, c1, o1hi, o1lo);
    } else {
        if (DO_L1)
            job_gate2<0>(s, winlds, bx, by, a2hi, Wlp_hi, blp, gdownl, part,
                         out0, t_out, c2, o2hi, Woutl, out1, t2);
        else
            job_gate2<1>(s, winlds, bx, by, a2hi, Wlp_hi, blp, gdownl, part,
                         out0, t_out, c2, o2hi, Woutl, out1, t2);
    }
}

__global__ __launch_bounds__(256, 2)
void logits_fb(const f16* Ahi, const f16* Alo, const f16* Bph, const f16* Bpl,
               const float* bias, const float* gu, float2* part, int t)
{
    __shared__ f16 s[4][4096];
    int lin = blockIdx.y * 4 + blockIdx.x;
    lin = swz_lin(lin, 256);
    const int bx = lin & 3, by = lin >> 2;
    job_logits(s, bx, by, Ahi, Alo, Bph, Bpl, bias, gu, part, t);
}

// ---------------- init4: four [8192x512,K=512] split GEMMs (z-select), tanh epilogue ----------------
__global__ __launch_bounds__(256, 2)
void init4(const f16* __restrict__ i1hi, const f16* __restrict__ i1lo,
           const f16* __restrict__ i2hi, const f16* __restrict__ i2lo,
           const f16* __restrict__ Whp_hi, const f16* __restrict__ Whp_lo,
           const f16* __restrict__ Wcp_hi, const f16* __restrict__ Wcp_lo,
           const f16* __restrict__ Whlp_hi, const f16* __restrict__ Whlp_lo,
           const f16* __restrict__ Wclp_hi, const f16* __restrict__ Wclp_lo,
           const float* __restrict__ b_hup, const float* __restrict__ b_cup,
           const float* __restrict__ b_hupl, const float* __restrict__ b_cupl,
           float* __restrict__ c1, float* __restrict__ c2,
           f16* __restrict__ h1hi, f16* __restrict__ h1lo, f16* __restrict__ h2hi)
{
    __shared__ f16 s[4][4096];
    const int z = blockIdx.z;
    const f16 *Ahi, *Alo, *Bh, *Bl;
    const float* bias;
    switch (z) {
        case 0: Ahi = i1hi; Alo = i1lo; Bh = Whp_hi;  Bl = Whp_lo;  bias = b_hup;  break;
        case 1: Ahi = i1hi; Alo = i1lo; Bh = Wcp_hi;  Bl = Wcp_lo;  bias = b_cup;  break;
        case 2: Ahi = i2hi; Alo = i2lo; Bh = Whlp_hi; Bl = Whlp_lo; bias = b_hupl; break;
        default: Ahi = i2hi; Alo = i2lo; Bh = Wclp_hi; Bl = Wclp_lo; bias = b_cupl; break;
    }
    int bx = blockIdx.x, by = blockIdx.y;
    swz_xcd(bx, by);
    const int bm = by << 7;
    const int tid = threadIdx.x;
    const int wid = tid >> 6, lane = tid & 63;
    const int wr = ((wid >> 1) & 1) << 6;
    const int wc2 = wid & 1;

    f32x4 acc[4][4];
#pragma unroll
    for (int i = 0; i < 4; ++i)
#pragma unroll
        for (int j = 0; j < 4; ++j) acc[i][j] = (f32x4)(0.0f);

    core3<1>(Ahi, Alo, Bh, Bl, s[0], s[1], s[2], s[3], bm, bx, wid, lane, wr, wc2, acc);

    const int r16 = lane & 15, rg = lane >> 4;
#pragma unroll
    for (int i = 0; i < 4; ++i) {
#pragma unroll
        for (int r = 0; r < 4; ++r) {
            const int row = bm + wr + i * 16 + rg * 4 + r;
#pragma unroll
            for (int j = 0; j < 4; ++j) {
                const int col = (bx << 7) + (wc2 << 6) + j * 16 + r16;
                float v = tanhf(acc[i][j][r] + bias[col]);
                const size_t idx = (size_t)row * NH + col;
                if (z == 0) {
                    const f16 a = (f16)v;
                    h1hi[idx] = a;
                    h1lo[idx] = (f16)(v - (float)a);
                } else if (z == 1) c1[idx] = v;
                else if (z == 2) h2hi[idx] = (f16)v;
                else c2[idx] = v;
            }
        }
    }
}

// ---------------- latent init GEMM (f32 vector, K=128), tanh + split-f16 output ----------------
__global__ __launch_bounds__(256)
void gemm128_split(const float* __restrict__ A,
                   const float* __restrict__ W0, const float* __restrict__ b0,
                   const float* __restrict__ W1, const float* __restrict__ b1,
                   f16* __restrict__ o0hi, f16* __restrict__ o0lo,
                   f16* __restrict__ o1hi, f16* __restrict__ o1lo)
{
    const float* W = blockIdx.z ? W1 : W0;
    const float* bias = blockIdx.z ? b1 : b0;
    f16* ohi = blockIdx.z ? o1hi : o0hi;
    f16* olo = blockIdx.z ? o1lo : o0lo;
    __shared__ float As[16][128];
    __shared__ float Bs[16][128];
    const int bm = blockIdx.y << 7, bn = blockIdx.x << 7;
    const int tid = threadIdx.x;
    const int tx = tid & 15, ty = tid >> 4;
    const int sar = tid >> 1, sac = (tid & 1) << 3;
    const int sbk = tid >> 4, sbc = (tid & 15) << 3;
    float acc[2][2][4][4] = {};
    const float* Ap = A + (size_t)(bm + sar) * NZ + sac;
    const float* Wp = W + (size_t)sbk * NH + bn + sbc;
    for (int kb = 0; kb < NZ; kb += 16) {
        const float4 av0 = *(const float4*)(Ap + kb);
        const float4 av1 = *(const float4*)(Ap + kb + 4);
        const float4 bv0 = *(const float4*)(Wp + (size_t)kb * NH);
        const float4 bv1 = *(const float4*)(Wp + (size_t)kb * NH + 4);
        __syncthreads();
        As[sac + 0][sar] = av0.x; As[sac + 1][sar] = av0.y;
        As[sac + 2][sar] = av0.z; As[sac + 3][sar] = av0.w;
        As[sac + 4][sar] = av1.x; As[sac + 5][sar] = av1.y;
        As[sac + 6][sar] = av1.z; As[sac + 7][sar] = av1.w;
        *(float4*)&Bs[sbk][sbc] = bv0;
        *(float4*)&Bs[sbk][sbc + 4] = bv1;
        __syncthreads();
#pragma unroll
        for (int kk = 0; kk < 16; ++kk) {
            float a[2][4], b[2][4];
            *(float4*)a[0] = *(const float4*)&As[kk][ty << 2];
            *(float4*)a[1] = *(const float4*)&As[kk][64 + (ty << 2)];
            *(float4*)b[0] = *(const float4*)&Bs[kk][tx << 2];
            *(float4*)b[1] = *(const float4*)&Bs[kk][64 + (tx << 2)];
#pragma unroll
            for (int rh = 0; rh < 2; ++rh)
#pragma unroll
                for (int ch = 0; ch < 2; ++ch)
#pragma unroll
                    for (int i = 0; i < 4; ++i)
#pragma unroll
                        for (int j = 0; j < 4; ++j)
                            acc[rh][ch][i][j] = fmaf(a[rh][i], b[ch][j], acc[rh][ch][i][j]);
        }
    }
    float4 bi4[2];
    bi4[0] = *(const float4*)(bias + bn + (tx << 2));
    bi4[1] = *(const float4*)(bias + bn + 64 + (tx << 2));
    const float bia[2][4] = {{bi4[0].x, bi4[0].y, bi4[0].z, bi4[0].w},
                             {bi4[1].x, bi4[1].y, bi4[1].z, bi4[1].w}};
#pragma unroll
    for (int rh = 0; rh < 2; ++rh)
#pragma unroll
        for (int i = 0; i < 4; ++i) {
            const int row = bm + rh * 64 + (ty << 2) + i;
#pragma unroll
            for (int ch = 0; ch < 2; ++ch) {
                const int col = bn + ch * 64 + (tx << 2);
#pragma unroll
                for (int j = 0; j < 4; ++j) {
                    const float v = tanhf(acc[rh][ch][i][j] + bia[ch][j]);
                    const size_t idx = (size_t)row * NH + col + j;
                    const f16 a = (f16)v;
                    ohi[idx] = a;
                    olo[idx] = (f16)(v - (float)a);
                }
            }
        }
}

// ---------------- gdown pair: C = W_down{,l} @ W_lstm[:128] (f32 vector), permuted cols ----------------
__global__ __launch_bounds__(256)
void gemm128_gdown(const float* __restrict__ A0, const float* __restrict__ A1,
                   const float* __restrict__ W,
                   float* __restrict__ C0, float* __restrict__ C1)
{
    const float* A = blockIdx.z ? A1 : A0;
    float* C = blockIdx.z ? C1 : C0;
    __shared__ float As[16][128];
    __shared__ float Bs[16][128];
    const int bm = blockIdx.y << 7, bn = blockIdx.x << 7;
    const int tid = threadIdx.x;
    const int tx = tid & 15, ty = tid >> 4;
    const int sar = tid >> 1, sac = (tid & 1) << 3;
    const int sbk = tid >> 4, sbc = (tid & 15) << 3;
    float acc[2][2][4][4] = {};
    const float* Ap = A + (size_t)(bm + sar) * NIN + sac;
    const float* Wp = W + (size_t)sbk * NG + bn + sbc;
    for (int kb = 0; kb < NIN; kb += 16) {
        const float4 av0 = *(const float4*)(Ap + kb);
        const float4 av1 = *(const float4*)(Ap + kb + 4);
        const float4 bv0 = *(const float4*)(Wp + (size_t)kb * NG);
        const float4 bv1 = *(const float4*)(Wp + (size_t)kb * NG + 4);
        __syncthreads();
        As[sac + 0][sar] = av0.x; As[sac + 1][sar] = av0.y;
        As[sac + 2][sar] = av0.z; As[sac + 3][sar] = av0.w;
        As[sac + 4][sar] = av1.x; As[sac + 5][sar] = av1.y;
        As[sac + 6][sar] = av1.z; As[sac + 7][sar] = av1.w;
        *(float4*)&Bs[sbk][sbc] = bv0;
        *(float4*)&Bs[sbk][sbc + 4] = bv1;
        __syncthreads();
#pragma unroll
        for (int kk = 0; kk < 16; ++kk) {
            float a[2][4], b[2][4];
            *(float4*)a[0] = *(const float4*)&As[kk][ty << 2];
            *(float4*)a[1] = *(const float4*)&As[kk][64 + (ty << 2)];
            *(float4*)b[0] = *(const float4*)&Bs[kk][tx << 2];
            *(float4*)b[1] = *(const float4*)&Bs[kk][64 + (tx << 2)];
#pragma unroll
            for (int rh = 0; rh < 2; ++rh)
#pragma unroll
                for (int ch = 0; ch < 2; ++ch)
#pragma unroll
                    for (int i = 0; i < 4; ++i)
#pragma unroll
                        for (int j = 0; j < 4; ++j)
                            acc[rh][ch][i][j] = fmaf(a[rh][i], b[ch][j], acc[rh][ch][i][j]);
        }
    }
#pragma unroll
    for (int rh = 0; rh < 2; ++rh)
#pragma unroll
        for (int i = 0; i < 4; ++i) {
            const int row = bm + rh * 64 + (ty << 2) + i;
#pragma unroll
            for (int ch = 0; ch < 2; ++ch) {
                const int col = bn + ch * 64 + (tx << 2);
                *(float4*)(C + (size_t)row * NG + cperm(col)) =
                    make_float4(acc[rh][ch][i][0], acc[rh][ch][i][1],
                                acc[rh][ch][i][2], acc[rh][ch][i][3]);
            }
        }
}

// ---------------- pack all 6 weights (z-select) ----------------
__global__ __launch_bounds__(256)
void tsplit_pack_all(const float* __restrict__ Wl, const float* __restrict__ Wup,
                     const float* __restrict__ Whp, const float* __restrict__ Wcp,
                     const float* __restrict__ Whlp, const float* __restrict__ Wclp,
                     f16* __restrict__ Wlp_hi, f16* __restrict__ Wlp_lo,
                     f16* __restrict__ Wup_hi, f16* __restrict__ Wup_lo,
                     f16* __restrict__ Whp_hi, f16* __restrict__ Whp_lo,
                     f16* __restrict__ Wcp_hi, f16* __restrict__ Wcp_lo,
                     f16* __restrict__ Whlp_hi, f16* __restrict__ Whlp_lo,
                     f16* __restrict__ Wclp_hi, f16* __restrict__ Wclp_lo)
{
    const int z = blockIdx.z;
    const int nblkcnt = (z == 0) ? 16 : 4;
    if ((int)blockIdx.y >= nblkcnt) return;
    const float* src;
    int ldin, perm;
    f16 *ph, *pl;
    switch (z) {
        case 0: src = Wl;   ldin = NG; perm = 1; ph = Wlp_hi;  pl = Wlp_lo;  break;
        case 1: src = Wup;  ldin = NH; perm = 0; ph = Wup_hi;  pl = Wup_lo;  break;
        case 2: src = Whp;  ldin = NH; perm = 0; ph = Whp_hi;  pl = Whp_lo;  break;
        case 3: src = Wcp;  ldin = NH; perm = 0; ph = Wcp_hi;  pl = Wcp_lo;  break;
        case 4: src = Whlp; ldin = NH; perm = 0; ph = Whlp_hi; pl = Whlp_lo; break;
        default: src = Wclp; ldin = NH; perm = 0; ph = Wclp_hi; pl = Wclp_lo; break;
    }
    const int kt = blockIdx.x;
    const int nblk = blockIdx.y;
#pragma unroll
    for (int q = 0; q < 2; ++q) {
        const int cch = threadIdx.x + q * 256;
        const int wc2 = cch >> 8, f = (cch >> 6) & 3, slc = (cch >> 4) & 3, r16 = cch & 15;
        const int n = (nblk << 7) + (wc2 << 6) + (f << 4) + r16;
        const int ncol = perm ? oc_of(n) : n;
        const int k0 = (kt << 5) + (slc << 3);
        f16x8 h8, l8;
#pragma unroll
        for (int e = 0; e < 8; ++e) {
            const float v = src[(size_t)(k0 + e) * ldin + ncol];
            const f16 hi = (f16)v;
            h8[e] = hi;
            l8[e] = (f16)(v - (float)hi);
        }
        const size_t off = ((((size_t)nblk << 4) + kt) << 12) + (size_t)cch * 8;
        *(f16x8*)(ph + off) = h8;
        *(f16x8*)(pl + off) = l8;
    }
}

__global__ __launch_bounds__(256)
void permb(const float* __restrict__ b, float* __restrict__ bp)
{
    const int c = blockIdx.x * 256 + threadIdx.x;
    bp[c] = b[oc_of(c)];
}

__global__ __launch_bounds__(256)
void out1_init(float* __restrict__ out1, const float* __restrict__ boutl)
{
    const size_t i = (size_t)blockIdx.x * 256 + threadIdx.x;
    out1[i] = boutl[0];
}

extern "C" void kernel_launch(void* const* d_in, const int* in_sizes, int n_in,
                              void* d_out, int out_size, void* d_ws, size_t ws_size,
                              hipStream_t stream)
{
    const float* latent  = (const float*)d_in[0];
    const float* gu      = (const float*)d_in[2];
    const float* W_int   = (const float*)d_in[3];
    const float* b_int   = (const float*)d_in[4];
    const float* W_intl  = (const float*)d_in[5];
    const float* b_intl  = (const float*)d_in[6];
    const float* W_hup   = (const float*)d_in[7];
    const float* b_hup   = (const float*)d_in[8];
    const float* W_cup   = (const float*)d_in[9];
    const float* b_cup   = (const float*)d_in[10];
    const float* W_hupl  = (const float*)d_in[11];
    const float* b_hupl  = (const float*)d_in[12];
    const float* W_cupl  = (const float*)d_in[13];
    const float* b_cupl  = (const float*)d_in[14];
    const float* W_lstm  = (const float*)d_in[15];
    const float* b_lstm  = (const float*)d_in[16];
    const float* W_up    = (const float*)d_in[17];
    const float* b_up    = (const float*)d_in[18];
    const float* W_down  = (const float*)d_in[19];
    const float* W_downl = (const float*)d_in[20];
    const float* W_outl  = (const float*)d_in[21];
    const float* b_outl  = (const float*)d_in[22];

    float* out0 = (float*)d_out;                 // [B, RW, N]
    float* out1 = out0 + (size_t)NB * NRW * NN;  // [B, RW, 1]

    // workspace
    float* ws     = (float*)d_ws;
    float* c1     = ws;                               // NB*NH
    float* c2     = c1 + (size_t)NB * NH;             // NB*NH
    float* gdown  = c2 + (size_t)NB * NH;             // NN*NG (permuted cols)
    float* gdownl = gdown + (size_t)NN * NG;          // NN*NG
    float* blp    = gdownl + (size_t)NN * NG;         // NG
    float2* part  = (float2*)(blp + NG);              // NB*8
    f16* fp = (f16*)(part + (size_t)NB * 8);
    f16* h1hi0 = fp;                 fp += (size_t)NB * NH;
    f16* h1lo0 = fp;                 fp += (size_t)NB * NH;
    f16* h1hi1 = fp;                 fp += (size_t)NB * NH;
    f16* h1lo1 = fp;                 fp += (size_t)NB * NH;
    f16* h2hi0 = fp;                 fp += (size_t)NB * NH;
    f16* h2hi1 = fp;                 fp += (size_t)NB * NH;
    f16* i1hi = fp;                  fp += (size_t)NB * NH;
    f16* i1lo = fp;                  fp += (size_t)NB * NH;
    f16* i2hi = fp;                  fp += (size_t)NB * NH;
    f16* i2lo = fp;                  fp += (size_t)NB * NH;
    f16* Wlp_hi = fp;                fp += (size_t)NG * NH;
    f16* Wlp_lo = fp;                fp += (size_t)NG * NH;
    f16* Wup_hi = fp;                fp += (size_t)NN * NH;
    f16* Wup_lo = fp;                fp += (size_t)NN * NH;
    f16* Whp_hi = fp;                fp += (size_t)NH * NH;
    f16* Whp_lo = fp;                fp += (size_t)NH * NH;
    f16* Wcp_hi = fp;                fp += (size_t)NH * NH;
    f16* Wcp_lo = fp;                fp += (size_t)NH * NH;
    f16* Whlp_hi = fp;               fp += (size_t)NH * NH;
    f16* Whlp_lo = fp;               fp += (size_t)NH * NH;
    f16* Wclp_hi = fp;               fp += (size_t)NH * NH;
    f16* Wclp_lo = fp;               fp += (size_t)NH * NH;

    const dim3 blk(256);

    // ---- prep ----
    tsplit_pack_all<<<dim3(16, 16, 6), blk, 0, stream>>>(
        W_lstm + (size_t)NIN * NG, W_up, W_hup, W_cup, W_hupl, W_cupl,
        Wlp_hi, Wlp_lo, Wup_hi, Wup_lo, Whp_hi, Whp_lo, Wcp_hi, Wcp_lo,
        Whlp_hi, Whlp_lo, Wclp_hi, Wclp_lo);
    permb<<<dim3(NG / 256), blk, 0, stream>>>(b_lstm, blp);
    gemm128_gdown<<<dim3(NG / 128, NN / 128, 2), blk, 0, stream>>>(W_down, W_downl, W_lstm,
                                                                   gdown, gdownl);
    gemm128_split<<<dim3(NH / 128, NB / 128, 2), blk, 0, stream>>>(latent, W_int, b_int,
                                                                   W_intl, b_intl,
                                                                   i1hi, i1lo, i2hi, i2lo);
    init4<<<dim3(NH / 128, NB / 128, 4), blk, 0, stream>>>(
        i1hi, i1lo, i2hi, i2lo,
        Whp_hi, Whp_lo, Wcp_hi, Wcp_lo, Whlp_hi, Whlp_lo, Wclp_hi, Wclp_lo,
        b_hup, b_cup, b_hupl, b_cupl,
        c1, c2, h1hi0, h1lo0, h2hi0);
    out1_init<<<dim3(NB * NRW / 256), blk, 0, stream>>>(out1, b_outl);

    // ---- main loop: persistent cooperative kernel ----
    int maxb = 0;
    hipOccupancyMaxActiveBlocksPerMultiprocessor(&maxb, persist_loop, 256, 0);
    if (maxb < 1) maxb = 1;
    if (maxb > 2) maxb = 2;
    const int nblk_coop = maxb * 256;

    void* cargs[] = {
        (void*)&Wlp_hi, (void*)&Wlp_lo, (void*)&Wup_hi, (void*)&Wup_lo,
        (void*)&blp, (void*)&b_up, (void*)&gdown, (void*)&gdownl,
        (void*)&gu, (void*)&W_outl,
        (void*)&part, (void*)&out0, (void*)&out1,
        (void*)&c1, (void*)&c2,
        (void*)&h1hi0, (void*)&h1lo0, (void*)&h1hi1, (void*)&h1lo1,
        (void*)&h2hi0, (void*)&h2hi1};

    hipError_t ce = hipLaunchCooperativeKernel(persist_loop, dim3(nblk_coop), blk,
                                               cargs, 0u, stream);
    if (ce != hipSuccess) {
        (void)hipGetLastError();   // clear; fall back to multi-launch sequence
        f16* h1hiA[2] = {h1hi0, h1hi1};
        f16* h1loA[2] = {h1lo0, h1lo1};
        f16* h2hiA[2] = {h2hi0, h2hi1};
        const dim3 g1(16, 64, 1), g2(16, 64, 2), gl(4, 64);

        fused_gate_fb<1, 0><<<g1, blk, 0, stream>>>(h1hiA[0], h1loA[0], nullptr,
                                                    Wlp_hi, Wlp_lo, blp, gdown, gdownl,
                                                    nullptr, out0, 0,
                                                    c1, h1hiA[1], h1loA[1],
                                                    nullptr, nullptr, W_outl, out1, 0);
        logits_fb<<<gl, blk, 0, stream>>>(h1hiA[1], h1loA[1], Wup_hi, Wup_lo,
                                          b_up, gu, part, 0);
        int c1i = 1, c2i = 0;
        for (int t = 0; t < NRW - 1; ++t) {
            const int n1 = c1i ^ 1, n2 = c2i ^ 1;
            fused_gate_fb<1, 1><<<g2, blk, 0, stream>>>(h1hiA[c1i], h1loA[c1i], h2hiA[c2i],
                                                        Wlp_hi, Wlp_lo, blp, gdown, gdownl,
                                                        part, out0, t,
                                                        c1, h1hiA[n1], h1loA[n1],
                                                        c2, h2hiA[n2], W_outl, out1, t);
            logits_fb<<<gl, blk, 0, stream>>>(h1hiA[n1], h1loA[n1], Wup_hi, Wup_lo,
                                              b_up, gu, part, t + 1);
            c1i = n1;
            c2i = n2;
        }
        fused_gate_fb<0, 1><<<g1, blk, 0, stream>>>(nullptr, nullptr, h2hiA[c2i],
                                                    Wlp_hi, Wlp_lo, blp, gdown, gdownl,
                                                    part, out0, NRW - 1,
                                                    nullptr, nullptr, nullptr,
                                                    c2, h2hiA[c2i ^ 1], W_outl, out1, NRW - 1);
    }
}

// Round 14
// 2567.679 us; speedup vs baseline: 2.1299x; 2.1299x over previous
//
#include <hip/hip_runtime.h>

#define NB 8192
#define NH 512
#define NZ 128
#define NIN 128
#define NN 512
#define NRW 16
#define NG 2048   // 4*NH

typedef _Float16 f16;
typedef _Float16 f16x8 __attribute__((ext_vector_type(8)));
typedef float f32x4 __attribute__((ext_vector_type(4)));

__device__ __forceinline__ float sigm(float x) { return 1.0f / (1.0f + expf(-x)); }

// gate-interleaved column permutation: stored col c <- original col oc(c)
__device__ __forceinline__ int oc_of(int c)
{
    return (((c >> 4) & 3) << 9) + ((c >> 6) << 4) + (c & 15);
}
__device__ __forceinline__ int cperm(int j)
{
    return (j & 15) | (((j >> 4) & 31) << 6) | (((j >> 9) & 3) << 4);
}

// Bijective XCD-aware block swizzle (nwg % 8 == 0 for all our grids).
__device__ __forceinline__ void swz_xcd(int& bx, int& by)
{
    const int gx = gridDim.x;
    const int nwg = gx * gridDim.y;
    int lin = by * gx + bx;
    lin = (lin & 7) * (nwg >> 3) + (lin >> 3);
    const int sh = 31 - __clz(gx);
    bx = lin & (gx - 1);
    by = lin >> sh;
}

// ---------------- async 16B global->LDS ----------------
__device__ __forceinline__ void gload16(const f16* g, f16* l)
{
    __builtin_amdgcn_global_load_lds(
        (const __attribute__((address_space(1))) void*)g,
        (__attribute__((address_space(3))) void*)l, 16, 0, 0);
}

__device__ __forceinline__ int swz4(int row) { return (row & 3) ^ ((row >> 2) & 3); }

// Stage one 128x32 f16 A-tile (8KB): linear LDS dest + inverse-swizzled global src.
__device__ __forceinline__ void stage_tile(f16* tilebase, const f16* src,
                                           int rowbase, int kb, int wid, int lane)
{
#pragma unroll
    for (int q = 0; q < 2; ++q) {
        const int iw = wid * 2 + q;
        const int chunk = (iw << 6) | lane;
        const int row = chunk >> 2;
        const int p = (chunk & 3) ^ swz4(row);
        const f16* g = src + (size_t)(rowbase + row) * NH + kb + (p << 3);
        gload16(g, tilebase + (iw << 9));
    }
}

// Stage one 64x32 f16 A-tile (4KB): 1 chunk per thread.
__device__ __forceinline__ void stage64(f16* tilebase, const f16* src,
                                        int rowbase, int kb, int wid, int lane)
{
    const int chunk = (wid << 6) | lane;
    const int row = chunk >> 2;
    const int p = (chunk & 3) ^ swz4(row);
    const f16* g = src + (size_t)(rowbase + row) * NH + kb + (p << 3);
    gload16(g, tilebase + (wid << 9));
}

__device__ __forceinline__ f16x8 frag(const f16* tile, int row, int sl)
{
    return *(const f16x8*)(tile + row * 32 + ((sl ^ swz4(row)) << 3));
}

__device__ __forceinline__ void readA(f16x8 (&a)[4], const f16* sbuf, int wr, int r16, int sl)
{
#pragma unroll
    for (int f = 0; f < 4; ++f) a[f] = frag(sbuf, wr + f * 16 + r16, sl);
}

// Packed-B frag load: per (nblk,kt) an 8KB chunk (4096 f16).
// group g = wc2*256 + f*64 + lane  ->  element offset wc2*2048 + f*512 + lane*8.
__device__ __forceinline__ void loadBfr(f16x8 (&d)[4], const f16* p, size_t base)
{
#pragma unroll
    for (int f = 0; f < 4; ++f) d[f] = *(const f16x8*)(p + base + f * 512);
}

__device__ __forceinline__ f32x4 MM(const f16x8 a, const f16x8 b, f32x4 c)
{
    return __builtin_amdgcn_mfma_f32_16x16x32_f16(a, b, c, 0, 0, 0);
}

// ---------------- single-acc split core: acc = (Ahi+Alo)(Bhi+Blo) [al*bl dropped] ----------------
// A staged in LDS (double-buffered); B read directly from packed global (L2-hot).
// 128-row tile, K = 512 (16 k-tiles of 32).
template<int SPLIT>
__device__ __forceinline__ void core3(const f16* Ahi, const f16* Alo,
                                      const f16* Bph, const f16* Bpl,
                                      f16* s0h, f16* s0l, f16* s1h, f16* s1l,
                                      int bm, int bnblk, int wid, int lane, int wr, int wc2,
                                      f32x4 (&acc)[4][4])
{
    const int r16 = lane & 15, sl = lane >> 4;
    const size_t bwoff = (size_t)(wc2 << 11) + lane * 8;
    f16x8 bAh[4], bAl[4], bBh[4], bBl[4];

    stage_tile(s0h, Ahi, bm, 0, wid, lane);
    if (SPLIT) stage_tile(s0l, Alo, bm, 0, wid, lane);
    loadBfr(bAh, Bph, (((size_t)bnblk << 4) << 12) + bwoff);
    if (SPLIT) loadBfr(bAl, Bpl, (((size_t)bnblk << 4) << 12) + bwoff);

#pragma unroll 1
    for (int kt = 0; kt < 16; kt += 2) {
        __syncthreads();
        {
            const int kn = kt + 1;
            stage_tile(s1h, Ahi, bm, kn << 5, wid, lane);
            if (SPLIT) stage_tile(s1l, Alo, bm, kn << 5, wid, lane);
            loadBfr(bBh, Bph, ((((size_t)bnblk << 4) + kn) << 12) + bwoff);
            if (SPLIT) loadBfr(bBl, Bpl, ((((size_t)bnblk << 4) + kn) << 12) + bwoff);
        }
        f16x8 ah[4], al[4];
        readA(ah, s0h, wr, r16, sl);
        if (SPLIT) readA(al, s0l, wr, r16, sl);
        __builtin_amdgcn_s_setprio(1);
#pragma unroll
        for (int i = 0; i < 4; ++i)
#pragma unroll
            for (int j = 0; j < 4; ++j) {
                acc[i][j] = MM(ah[i], bAh[j], acc[i][j]);
                if (SPLIT) {
                    acc[i][j] = MM(al[i], bAh[j], acc[i][j]);
                    acc[i][j] = MM(ah[i], bAl[j], acc[i][j]);
                }
            }
        __builtin_amdgcn_s_setprio(0);
        __syncthreads();
        if (kt + 2 < 16) {
            const int kn = kt + 2;
            stage_tile(s0h, Ahi, bm, kn << 5, wid, lane);
            if (SPLIT) stage_tile(s0l, Alo, bm, kn << 5, wid, lane);
            loadBfr(bAh, Bph, ((((size_t)bnblk << 4) + kn) << 12) + bwoff);
            if (SPLIT) loadBfr(bAl, Bpl, ((((size_t)bnblk << 4) + kn) << 12) + bwoff);
        }
        readA(ah, s1h, wr, r16, sl);
        if (SPLIT) readA(al, s1l, wr, r16, sl);
        __builtin_amdgcn_s_setprio(1);
#pragma unroll
        for (int i = 0; i < 4; ++i)
#pragma unroll
            for (int j = 0; j < 4; ++j) {
                acc[i][j] = MM(ah[i], bBh[j], acc[i][j]);
                if (SPLIT) {
                    acc[i][j] = MM(al[i], bBh[j], acc[i][j]);
                    acc[i][j] = MM(ah[i], bBl[j], acc[i][j]);
                }
            }
        __builtin_amdgcn_s_setprio(0);
    }
}

// ---------------- 64-row 3-pass core (logits): acc[2][4] ----------------
__device__ __forceinline__ void core64(const f16* Ahi, const f16* Alo,
                                       const f16* Bph, const f16* Bpl,
                                       f16* s0h, f16* s0l, f16* s1h, f16* s1l,
                                       int bm, int bnblk, int wid, int lane, int wr, int wc2,
                                       f32x4 (&acc)[2][4])
{
    const int r16 = lane & 15, sl = lane >> 4;
    const size_t bwoff = (size_t)(wc2 << 11) + lane * 8;
    f16x8 bAh[4], bAl[4], bBh[4], bBl[4];

    stage64(s0h, Ahi, bm, 0, wid, lane);
    stage64(s0l, Alo, bm, 0, wid, lane);
    loadBfr(bAh, Bph, (((size_t)bnblk << 4) << 12) + bwoff);
    loadBfr(bAl, Bpl, (((size_t)bnblk << 4) << 12) + bwoff);

#pragma unroll 1
    for (int kt = 0; kt < 16; kt += 2) {
        __syncthreads();
        {
            const int kn = kt + 1;
            stage64(s1h, Ahi, bm, kn << 5, wid, lane);
            stage64(s1l, Alo, bm, kn << 5, wid, lane);
            loadBfr(bBh, Bph, ((((size_t)bnblk << 4) + kn) << 12) + bwoff);
            loadBfr(bBl, Bpl, ((((size_t)bnblk << 4) + kn) << 12) + bwoff);
        }
        f16x8 ah[2], al[2];
#pragma unroll
        for (int f = 0; f < 2; ++f) {
            ah[f] = frag(s0h, wr + f * 16 + r16, sl);
            al[f] = frag(s0l, wr + f * 16 + r16, sl);
        }
        __builtin_amdgcn_s_setprio(1);
#pragma unroll
        for (int i = 0; i < 2; ++i)
#pragma unroll
            for (int j = 0; j < 4; ++j) {
                acc[i][j] = MM(ah[i], bAh[j], acc[i][j]);
                acc[i][j] = MM(al[i], bAh[j], acc[i][j]);
                acc[i][j] = MM(ah[i], bAl[j], acc[i][j]);
            }
        __builtin_amdgcn_s_setprio(0);
        __syncthreads();
        if (kt + 2 < 16) {
            const int kn = kt + 2;
            stage64(s0h, Ahi, bm, kn << 5, wid, lane);
            stage64(s0l, Alo, bm, kn << 5, wid, lane);
            loadBfr(bAh, Bph, ((((size_t)bnblk << 4) + kn) << 12) + bwoff);
            loadBfr(bAl, Bpl, ((((size_t)bnblk << 4) + kn) << 12) + bwoff);
        }
#pragma unroll
        for (int f = 0; f < 2; ++f) {
            ah[f] = frag(s1h, wr + f * 16 + r16, sl);
            al[f] = frag(s1l, wr + f * 16 + r16, sl);
        }
        __builtin_amdgcn_s_setprio(1);
#pragma unroll
        for (int i = 0; i < 2; ++i)
#pragma unroll
            for (int j = 0; j < 4; ++j) {
                acc[i][j] = MM(ah[i], bBh[j], acc[i][j]);
                acc[i][j] = MM(al[i], bBh[j], acc[i][j]);
                acc[i][j] = MM(ah[i], bBl[j], acc[i][j]);
            }
        __builtin_amdgcn_s_setprio(0);
    }
}

// ---------------- dual-role fused gate kernel (round-12 structure) ----------------
template<int DO_L1, int DO_L2>
__global__ __launch_bounds__(256, 2)
void fused_gate(const f16* __restrict__ a1hi, const f16* __restrict__ a1lo,
                const f16* __restrict__ a2hi,
                const f16* __restrict__ Wlp_hi, const f16* __restrict__ Wlp_lo,
                const float* __restrict__ blp,
                const float* __restrict__ gdown, const float* __restrict__ gdownl,
                const float2* __restrict__ part,
                float* __restrict__ out0, int t_out,
                float* __restrict__ c1, f16* __restrict__ o1hi, f16* __restrict__ o1lo,
                float* __restrict__ c2, f16* __restrict__ o2hi,
                const float* __restrict__ Woutl, float* __restrict__ out1, int t2)
{
    __shared__ f16 s[4][4096];
    __shared__ int winlds[128];
    int bx = blockIdx.x, by = blockIdx.y;
    swz_xcd(bx, by);
    const int bm = by << 7;
    const int tid = threadIdx.x;
    const int wid = tid >> 6, lane = tid & 63;
    const int wr = ((wid >> 1) & 1) << 6;
    const int wc2 = wid & 1;
    const bool isL1 = DO_L1 && (!DO_L2 || blockIdx.z == 0);

    if (part != nullptr && tid < 128) {
        const float2* p = part + (size_t)(bm + tid) * 8;
        float best = -INFINITY;
        int bi = 0x7fffffff;
#pragma unroll
        for (int q = 0; q < 8; ++q) {
            const float2 pv = p[q];
            if (pv.x > best || (pv.x == best && (int)pv.y < bi)) { best = pv.x; bi = (int)pv.y; }
        }
        winlds[tid] = bi;
    }
    __syncthreads();

    f32x4 acc[4][4];
#pragma unroll
    for (int i = 0; i < 4; ++i)
#pragma unroll
        for (int j = 0; j < 4; ++j) acc[i][j] = (f32x4)(0.0f);

    const int m = lane & 15, rg = lane >> 4;
    const int colb = (bx << 7) + (wc2 << 6);
    const int jj = ((colb >> 6) << 4) + m;    // LSTM unit index (original space)
    float bi4[4];
#pragma unroll
    for (int g = 0; g < 4; ++g) bi4[g] = blp[colb + g * 16 + m];

    if (isL1) {
        core3<1>(a1hi, a1lo, Wlp_hi, Wlp_lo, s[0], s[1], s[2], s[3],
                 bm, bx, wid, lane, wr, wc2, acc);
#pragma unroll
        for (int i = 0; i < 4; ++i) {
#pragma unroll
            for (int r = 0; r < 4; ++r) {
                const int row = bm + wr + i * 16 + rg * 4 + r;
                float ex[4] = {0.f, 0.f, 0.f, 0.f};
                if (part != nullptr) {
                    const float* exr = gdown + (size_t)winlds[row - bm] * NG;
#pragma unroll
                    for (int g = 0; g < 4; ++g) ex[g] = exr[colb + g * 16 + m];
                }
                const float ig = acc[i][0][r] + bi4[0] + ex[0];
                const float gg = acc[i][1][r] + bi4[1] + ex[1];
                const float fg = acc[i][2][r] + bi4[2] + ex[2];
                const float og = acc[i][3][r] + bi4[3] + ex[3];
                const size_t cidx = (size_t)row * NH + jj;
                const float cx = c1[cidx];
                const float cy = cx * sigm(fg + 1.0f) + sigm(ig) * tanhf(gg);
                const float hy = sigm(og) * tanhf(cy);
                c1[cidx] = cy;
                const f16 a = (f16)hy;
                o1hi[cidx] = a;
                o1lo[cidx] = (f16)(hy - (float)a);
            }
        }
        if (part != nullptr) {
            const int rr = tid >> 1;
            const int cs = (bx << 5) + ((tid & 1) << 4);
            const int win = winlds[rr];
            float* orow = out0 + ((size_t)(bm + rr) * NRW + t_out) * NN + cs;
#pragma unroll
            for (int e = 0; e < 16; e += 4) {
                const int c0 = cs + e;
                *(float4*)(orow + e) = make_float4(c0 == win, c0 + 1 == win, c0 + 2 == win, c0 + 3 == win);
            }
        }
    } else {
        core3<0>(a2hi, nullptr, Wlp_hi, nullptr, s[0], nullptr, s[1], nullptr,
                 bm, bx, wid, lane, wr, wc2, acc);
        const float wout = Woutl[jj];
#pragma unroll
        for (int i = 0; i < 4; ++i) {
#pragma unroll
            for (int r = 0; r < 4; ++r) {
                const int row = bm + wr + i * 16 + rg * 4 + r;
                const float* exr = gdownl + (size_t)winlds[row - bm] * NG;
                float ex[4];
#pragma unroll
                for (int g = 0; g < 4; ++g) ex[g] = exr[colb + g * 16 + m];
                const float ig = acc[i][0][r] + bi4[0] + ex[0];
                const float gg = acc[i][1][r] + bi4[1] + ex[1];
                const float fg = acc[i][2][r] + bi4[2] + ex[2];
                const float og = acc[i][3][r] + bi4[3] + ex[3];
                const size_t cidx = (size_t)row * NH + jj;
                const float cx = c2[cidx];
                const float cy = cx * sigm(fg + 1.0f) + sigm(ig) * tanhf(gg);
                const float hy = sigm(og) * tanhf(cy);
                c2[cidx] = cy;
                o2hi[cidx] = (f16)hy;
                float pt = hy * wout;
#pragma unroll
                for (int msk = 1; msk < 16; msk <<= 1) pt += __shfl_xor(pt, msk);
                if (m == 0) atomicAdd(&out1[(size_t)row * NRW + t2], pt);
            }
        }
        if (!DO_L1) {
            const int rr = tid >> 1;
            const int cs = (bx << 5) + ((tid & 1) << 4);
            const int win = winlds[rr];
            float* orow = out0 + ((size_t)(bm + rr) * NRW + t_out) * NN + cs;
#pragma unroll
            for (int e = 0; e < 16; e += 4) {
                const int c0 = cs + e;
                *(float4*)(orow + e) = make_float4(c0 == win, c0 + 1 == win, c0 + 2 == win, c0 + 3 == win);
            }
        }
    }
}

// ---------------- logits GEMM + fused gumbel-argmax partials (64-row tiles, 512 blocks) ----------------
__global__ __launch_bounds__(256, 2)
void mfma_logits_argmax(const f16* __restrict__ Ahi, const f16* __restrict__ Alo,
                        const f16* __restrict__ Bph, const f16* __restrict__ Bpl,
                        const float* __restrict__ bias,
                        const float* __restrict__ gu,
                        float2* __restrict__ part, int t)
{
    __shared__ f16 s[4][2048];
    int bx = blockIdx.x, by = blockIdx.y;   // gridDim = (4, 128)
    swz_xcd(bx, by);
    const int bm = by << 6;                 // 64-row tile
    const int tid = threadIdx.x;
    const int wid = tid >> 6, lane = tid & 63;
    const int wr = ((wid >> 1) & 1) << 5;   // 32-row half
    const int wc2 = wid & 1;

    f32x4 acc[2][4];
#pragma unroll
    for (int i = 0; i < 2; ++i)
#pragma unroll
        for (int j = 0; j < 4; ++j) acc[i][j] = (f32x4)(0.0f);

    core64(Ahi, Alo, Bph, Bpl, s[0], s[1], s[2], s[3], bm, bx, wid, lane, wr, wc2, acc);

    const int r16 = lane & 15, rg = lane >> 4;
    const int cb = (bx << 1) + wc2;          // 64-col slice 0..7
    float bi[4];
#pragma unroll
    for (int j = 0; j < 4; ++j) bi[j] = bias[(bx << 7) + (wc2 << 6) + j * 16 + r16];

#pragma unroll
    for (int i = 0; i < 2; ++i) {
#pragma unroll
        for (int r = 0; r < 4; ++r) {
            const int row = bm + wr + i * 16 + rg * 4 + r;
            const float* urow = gu + ((size_t)t * NB + row) * NN;
            float best = -INFINITY;
            int bidx = 0x7fffffff;
#pragma unroll
            for (int j = 0; j < 4; ++j) {
                const int col = (bx << 7) + (wc2 << 6) + j * 16 + r16;
                const float u = urow[col];
                const float g = -logf(-logf(u + 1e-20f) + 1e-20f);
                const float v = acc[i][j][r] + bi[j] + g;
                if (v > best || (v == best && col < bidx)) { best = v; bidx = col; }
            }
#pragma unroll
            for (int msk = 1; msk < 16; msk <<= 1) {
                const float ov = __shfl_xor(best, msk);
                const int oi = __shfl_xor(bidx, msk);
                if (ov > best || (ov == best && oi < bidx)) { best = ov; bidx = oi; }
            }
            if (r16 == 0) part[(size_t)row * 8 + cb] = make_float2(best, (float)bidx);
        }
    }
}

// ---------------- init4: four [8192x512,K=512] split GEMMs (z-select), tanh epilogue ----------------
__global__ __launch_bounds__(256, 2)
void init4(const f16* __restrict__ i1hi, const f16* __restrict__ i1lo,
           const f16* __restrict__ i2hi, const f16* __restrict__ i2lo,
           const f16* __restrict__ Whp_hi, const f16* __restrict__ Whp_lo,
           const f16* __restrict__ Wcp_hi, const f16* __restrict__ Wcp_lo,
           const f16* __restrict__ Whlp_hi, const f16* __restrict__ Whlp_lo,
           const f16* __restrict__ Wclp_hi, const f16* __restrict__ Wclp_lo,
           const float* __restrict__ b_hup, const float* __restrict__ b_cup,
           const float* __restrict__ b_hupl, const float* __restrict__ b_cupl,
           float* __restrict__ c1, float* __restrict__ c2,
           f16* __restrict__ h1hi, f16* __restrict__ h1lo, f16* __restrict__ h2hi)
{
    __shared__ f16 s[4][4096];
    const int z = blockIdx.z;
    const f16 *Ahi, *Alo, *Bh, *Bl;
    const float* bias;
    switch (z) {
        case 0: Ahi = i1hi; Alo = i1lo; Bh = Whp_hi;  Bl = Whp_lo;  bias = b_hup;  break;
        case 1: Ahi = i1hi; Alo = i1lo; Bh = Wcp_hi;  Bl = Wcp_lo;  bias = b_cup;  break;
        case 2: Ahi = i2hi; Alo = i2lo; Bh = Whlp_hi; Bl = Whlp_lo; bias = b_hupl; break;
        default: Ahi = i2hi; Alo = i2lo; Bh = Wclp_hi; Bl = Wclp_lo; bias = b_cupl; break;
    }
    int bx = blockIdx.x, by = blockIdx.y;
    swz_xcd(bx, by);
    const int bm = by << 7;
    const int tid = threadIdx.x;
    const int wid = tid >> 6, lane = tid & 63;
    const int wr = ((wid >> 1) & 1) << 6;
    const int wc2 = wid & 1;

    f32x4 acc[4][4];
#pragma unroll
    for (int i = 0; i < 4; ++i)
#pragma unroll
        for (int j = 0; j < 4; ++j) acc[i][j] = (f32x4)(0.0f);

    core3<1>(Ahi, Alo, Bh, Bl, s[0], s[1], s[2], s[3], bm, bx, wid, lane, wr, wc2, acc);

    const int r16 = lane & 15, rg = lane >> 4;
#pragma unroll
    for (int i = 0; i < 4; ++i) {
#pragma unroll
        for (int r = 0; r < 4; ++r) {
            const int row = bm + wr + i * 16 + rg * 4 + r;
#pragma unroll
            for (int j = 0; j < 4; ++j) {
                const int col = (bx << 7) + (wc2 << 6) + j * 16 + r16;
                float v = tanhf(acc[i][j][r] + bias[col]);
                const size_t idx = (size_t)row * NH + col;
                if (z == 0) {
                    const f16 a = (f16)v;
                    h1hi[idx] = a;
                    h1lo[idx] = (f16)(v - (float)a);
                } else if (z == 1) c1[idx] = v;
                else if (z == 2) h2hi[idx] = (f16)v;
                else c2[idx] = v;
            }
        }
    }
}

// ---------------- latent init GEMM (f32 vector, K=128), tanh + split-f16 output ----------------
__global__ __launch_bounds__(256)
void gemm128_split(const float* __restrict__ A,
                   const float* __restrict__ W0, const float* __restrict__ b0,
                   const float* __restrict__ W1, const float* __restrict__ b1,
                   f16* __restrict__ o0hi, f16* __restrict__ o0lo,
                   f16* __restrict__ o1hi, f16* __restrict__ o1lo)
{
    const float* W = blockIdx.z ? W1 : W0;
    const float* bias = blockIdx.z ? b1 : b0;
    f16* ohi = blockIdx.z ? o1hi : o0hi;
    f16* olo = blockIdx.z ? o1lo : o0lo;
    __shared__ float As[16][128];
    __shared__ float Bs[16][128];
    const int bm = blockIdx.y << 7, bn = blockIdx.x << 7;
    const int tid = threadIdx.x;
    const int tx = tid & 15, ty = tid >> 4;
    const int sar = tid >> 1, sac = (tid & 1) << 3;
    const int sbk = tid >> 4, sbc = (tid & 15) << 3;
    float acc[2][2][4][4] = {};
    const float* Ap = A + (size_t)(bm + sar) * NZ + sac;
    const float* Wp = W + (size_t)sbk * NH + bn + sbc;
    for (int kb = 0; kb < NZ; kb += 16) {
        const float4 av0 = *(const float4*)(Ap + kb);
        const float4 av1 = *(const float4*)(Ap + kb + 4);
        const float4 bv0 = *(const float4*)(Wp + (size_t)kb * NH);
        const float4 bv1 = *(const float4*)(Wp + (size_t)kb * NH + 4);
        __syncthreads();
        As[sac + 0][sar] = av0.x; As[sac + 1][sar] = av0.y;
        As[sac + 2][sar] = av0.z; As[sac + 3][sar] = av0.w;
        As[sac + 4][sar] = av1.x; As[sac + 5][sar] = av1.y;
        As[sac + 6][sar] = av1.z; As[sac + 7][sar] = av1.w;
        *(float4*)&Bs[sbk][sbc] = bv0;
        *(float4*)&Bs[sbk][sbc + 4] = bv1;
        __syncthreads();
#pragma unroll
        for (int kk = 0; kk < 16; ++kk) {
            float a[2][4], b[2][4];
            *(float4*)a[0] = *(const float4*)&As[kk][ty << 2];
            *(float4*)a[1] = *(const float4*)&As[kk][64 + (ty << 2)];
            *(float4*)b[0] = *(const float4*)&Bs[kk][tx << 2];
            *(float4*)b[1] = *(const float4*)&Bs[kk][64 + (tx << 2)];
#pragma unroll
            for (int rh = 0; rh < 2; ++rh)
#pragma unroll
                for (int ch = 0; ch < 2; ++ch)
#pragma unroll
                    for (int i = 0; i < 4; ++i)
#pragma unroll
                        for (int j = 0; j < 4; ++j)
                            acc[rh][ch][i][j] = fmaf(a[rh][i], b[ch][j], acc[rh][ch][i][j]);
        }
    }
    float4 bi4[2];
    bi4[0] = *(const float4*)(bias + bn + (tx << 2));
    bi4[1] = *(const float4*)(bias + bn + 64 + (tx << 2));
    const float bia[2][4] = {{bi4[0].x, bi4[0].y, bi4[0].z, bi4[0].w},
                             {bi4[1].x, bi4[1].y, bi4[1].z, bi4[1].w}};
#pragma unroll
    for (int rh = 0; rh < 2; ++rh)
#pragma unroll
        for (int i = 0; i < 4; ++i) {
            const int row = bm + rh * 64 + (ty << 2) + i;
#pragma unroll
            for (int ch = 0; ch < 2; ++ch) {
                const int col = bn + ch * 64 + (tx << 2);
#pragma unroll
                for (int j = 0; j < 4; ++j) {
                    const float v = tanhf(acc[rh][ch][i][j] + bia[ch][j]);
                    const size_t idx = (size_t)row * NH + col + j;
                    const f16 a = (f16)v;
                    ohi[idx] = a;
                    olo[idx] = (f16)(v - (float)a);
                }
            }
        }
}

// ---------------- gdown pair: C = W_down{,l} @ W_lstm[:128] (f32 vector), permuted cols ----------------
__global__ __launch_bounds__(256)
void gemm128_gdown(const float* __restrict__ A0, const float* __restrict__ A1,
                   const float* __restrict__ W,
                   float* __restrict__ C0, float* __restrict__ C1)
{
    const float* A = blockIdx.z ? A1 : A0;
    float* C = blockIdx.z ? C1 : C0;
    __shared__ float As[16][128];
    __shared__ float Bs[16][128];
    const int bm = blockIdx.y << 7, bn = blockIdx.x << 7;
    const int tid = threadIdx.x;
    const int tx = tid & 15, ty = tid >> 4;
    const int sar = tid >> 1, sac = (tid & 1) << 3;
    const int sbk = tid >> 4, sbc = (tid & 15) << 3;
    float acc[2][2][4][4] = {};
    const float* Ap = A + (size_t)(bm + sar) * NIN + sac;
    const float* Wp = W + (size_t)sbk * NG + bn + sbc;
    for (int kb = 0; kb < NIN; kb += 16) {
        const float4 av0 = *(const float4*)(Ap + kb);
        const float4 av1 = *(const float4*)(Ap + kb + 4);
        const float4 bv0 = *(const float4*)(Wp + (size_t)kb * NG);
        const float4 bv1 = *(const float4*)(Wp + (size_t)kb * NG + 4);
        __syncthreads();
        As[sac + 0][sar] = av0.x; As[sac + 1][sar] = av0.y;
        As[sac + 2][sar] = av0.z; As[sac + 3][sar] = av0.w;
        As[sac + 4][sar] = av1.x; As[sac + 5][sar] = av1.y;
        As[sac + 6][sar] = av1.z; As[sac + 7][sar] = av1.w;
        *(float4*)&Bs[sbk][sbc] = bv0;
        *(float4*)&Bs[sbk][sbc + 4] = bv1;
        __syncthreads();
#pragma unroll
        for (int kk = 0; kk < 16; ++kk) {
            float a[2][4], b[2][4];
            *(float4*)a[0] = *(const float4*)&As[kk][ty << 2];
            *(float4*)a[1] = *(const float4*)&As[kk][64 + (ty << 2)];
            *(float4*)b[0] = *(const float4*)&Bs[kk][tx << 2];
            *(float4*)b[1] = *(const float4*)&Bs[kk][64 + (tx << 2)];
#pragma unroll
            for (int rh = 0; rh < 2; ++rh)
#pragma unroll
                for (int ch = 0; ch < 2; ++ch)
#pragma unroll
                    for (int i = 0; i < 4; ++i)
#pragma unroll
                        for (int j = 0; j < 4; ++j)
                            acc[rh][ch][i][j] = fmaf(a[rh][i], b[ch][j], acc[rh][ch][i][j]);
        }
    }
#pragma unroll
    for (int rh = 0; rh < 2; ++rh)
#pragma unroll
        for (int i = 0; i < 4; ++i) {
            const int row = bm + rh * 64 + (ty << 2) + i;
#pragma unroll
            for (int ch = 0; ch < 2; ++ch) {
                const int col = bn + ch * 64 + (tx << 2);
                *(float4*)(C + (size_t)row * NG + cperm(col)) =
                    make_float4(acc[rh][ch][i][0], acc[rh][ch][i][1],
                                acc[rh][ch][i][2], acc[rh][ch][i][3]);
            }
        }
}

// ---------------- pack all 6 weights (z-select) ----------------
__global__ __launch_bounds__(256)
void tsplit_pack_all(const float* __restrict__ Wl, const float* __restrict__ Wup,
                     const float* __restrict__ Whp, const float* __restrict__ Wcp,
                     const float* __restrict__ Whlp, const float* __restrict__ Wclp,
                     f16* __restrict__ Wlp_hi, f16* __restrict__ Wlp_lo,
                     f16* __restrict__ Wup_hi, f16* __restrict__ Wup_lo,
                     f16* __restrict__ Whp_hi, f16* __restrict__ Whp_lo,
                     f16* __restrict__ Wcp_hi, f16* __restrict__ Wcp_lo,
                     f16* __restrict__ Whlp_hi, f16* __restrict__ Whlp_lo,
                     f16* __restrict__ Wclp_hi, f16* __restrict__ Wclp_lo)
{
    const int z = blockIdx.z;
    const int nblkcnt = (z == 0) ? 16 : 4;
    if ((int)blockIdx.y >= nblkcnt) return;
    const float* src;
    int ldin, perm;
    f16 *ph, *pl;
    switch (z) {
        case 0: src = Wl;   ldin = NG; perm = 1; ph = Wlp_hi;  pl = Wlp_lo;  break;
        case 1: src = Wup;  ldin = NH; perm = 0; ph = Wup_hi;  pl = Wup_lo;  break;
        case 2: src = Whp;  ldin = NH; perm = 0; ph = Whp_hi;  pl = Whp_lo;  break;
        case 3: src = Wcp;  ldin = NH; perm = 0; ph = Wcp_hi;  pl = Wcp_lo;  break;
        case 4: src = Whlp; ldin = NH; perm = 0; ph = Whlp_hi; pl = Whlp_lo; break;
        default: src = Wclp; ldin = NH; perm = 0; ph = Wclp_hi; pl = Wclp_lo; break;
    }
    const int kt = blockIdx.x;
    const int nblk = blockIdx.y;
#pragma unroll
    for (int q = 0; q < 2; ++q) {
        const int cch = threadIdx.x + q * 256;
        const int wc2 = cch >> 8, f = (cch >> 6) & 3, slc = (cch >> 4) & 3, r16 = cch & 15;
        const int n = (nblk << 7) + (wc2 << 6) + (f << 4) + r16;
        const int ncol = perm ? oc_of(n) : n;
        const int k0 = (kt << 5) + (slc << 3);
        f16x8 h8, l8;
#pragma unroll
        for (int e = 0; e < 8; ++e) {
            const float v = src[(size_t)(k0 + e) * ldin + ncol];
            const f16 hi = (f16)v;
            h8[e] = hi;
            l8[e] = (f16)(v - (float)hi);
        }
        const size_t off = ((((size_t)nblk << 4) + kt) << 12) + (size_t)cch * 8;
        *(f16x8*)(ph + off) = h8;
        *(f16x8*)(pl + off) = l8;
    }
}

__global__ __launch_bounds__(256)
void permb(const float* __restrict__ b, float* __restrict__ bp)
{
    const int c = blockIdx.x * 256 + threadIdx.x;
    bp[c] = b[oc_of(c)];
}

__global__ __launch_bounds__(256)
void out1_init(float* __restrict__ out1, const float* __restrict__ boutl)
{
    const size_t i = (size_t)blockIdx.x * 256 + threadIdx.x;
    out1[i] = boutl[0];
}

extern "C" void kernel_launch(void* const* d_in, const int* in_sizes, int n_in,
                              void* d_out, int out_size, void* d_ws, size_t ws_size,
                              hipStream_t stream)
{
    const float* latent  = (const float*)d_in[0];
    const float* gu      = (const float*)d_in[2];
    const float* W_int   = (const float*)d_in[3];
    const float* b_int   = (const float*)d_in[4];
    const float* W_intl  = (const float*)d_in[5];
    const float* b_intl  = (const float*)d_in[6];
    const float* W_hup   = (const float*)d_in[7];
    const float* b_hup   = (const float*)d_in[8];
    const float* W_cup   = (const float*)d_in[9];
    const float* b_cup   = (const float*)d_in[10];
    const float* W_hupl  = (const float*)d_in[11];
    const float* b_hupl  = (const float*)d_in[12];
    const float* W_cupl  = (const float*)d_in[13];
    const float* b_cupl  = (const float*)d_in[14];
    const float* W_lstm  = (const float*)d_in[15];
    const float* b_lstm  = (const float*)d_in[16];
    const float* W_up    = (const float*)d_in[17];
    const float* b_up    = (const float*)d_in[18];
    const float* W_down  = (const float*)d_in[19];
    const float* W_downl = (const float*)d_in[20];
    const float* W_outl  = (const float*)d_in[21];
    const float* b_outl  = (const float*)d_in[22];

    float* out0 = (float*)d_out;                 // [B, RW, N]
    float* out1 = out0 + (size_t)NB * NRW * NN;  // [B, RW, 1]

    // workspace
    float* ws     = (float*)d_ws;
    float* c1     = ws;                               // NB*NH
    float* c2     = c1 + (size_t)NB * NH;             // NB*NH
    float* gdown  = c2 + (size_t)NB * NH;             // NN*NG (permuted cols)
    float* gdownl = gdown + (size_t)NN * NG;          // NN*NG
    float* blp    = gdownl + (size_t)NN * NG;         // NG
    float2* part  = (float2*)(blp + NG);              // NB*8
    f16* fp = (f16*)(part + (size_t)NB * 8);
    f16* h1hi[2]; f16* h1lo[2]; f16* h2hi[2];
    h1hi[0] = fp;                    fp += (size_t)NB * NH;
    h1lo[0] = fp;                    fp += (size_t)NB * NH;
    h1hi[1] = fp;                    fp += (size_t)NB * NH;
    h1lo[1] = fp;                    fp += (size_t)NB * NH;
    h2hi[0] = fp;                    fp += (size_t)NB * NH;
    h2hi[1] = fp;                    fp += (size_t)NB * NH;
    f16* i1hi = fp;                  fp += (size_t)NB * NH;
    f16* i1lo = fp;                  fp += (size_t)NB * NH;
    f16* i2hi = fp;                  fp += (size_t)NB * NH;
    f16* i2lo = fp;                  fp += (size_t)NB * NH;
    f16* Wlp_hi = fp;                fp += (size_t)NG * NH;   // packed, gate-perm
    f16* Wlp_lo = fp;                fp += (size_t)NG * NH;
    f16* Wup_hi = fp;                fp += (size_t)NN * NH;
    f16* Wup_lo = fp;                fp += (size_t)NN * NH;
    f16* Whp_hi = fp;                fp += (size_t)NH * NH;
    f16* Whp_lo = fp;                fp += (size_t)NH * NH;
    f16* Wcp_hi = fp;                fp += (size_t)NH * NH;
    f16* Wcp_lo = fp;                fp += (size_t)NH * NH;
    f16* Whlp_hi = fp;               fp += (size_t)NH * NH;
    f16* Whlp_lo = fp;               fp += (size_t)NH * NH;
    f16* Wclp_hi = fp;               fp += (size_t)NH * NH;
    f16* Wclp_lo = fp;               fp += (size_t)NH * NH;

    const dim3 blk(256);

    // ---- prep ----
    tsplit_pack_all<<<dim3(16, 16, 6), blk, 0, stream>>>(
        W_lstm + (size_t)NIN * NG, W_up, W_hup, W_cup, W_hupl, W_cupl,
        Wlp_hi, Wlp_lo, Wup_hi, Wup_lo, Whp_hi, Whp_lo, Wcp_hi, Wcp_lo,
        Whlp_hi, Whlp_lo, Wclp_hi, Wclp_lo);
    permb<<<dim3(NG / 256), blk, 0, stream>>>(b_lstm, blp);
    gemm128_gdown<<<dim3(NG / 128, NN / 128, 2), blk, 0, stream>>>(W_down, W_downl, W_lstm,
                                                                   gdown, gdownl);
    gemm128_split<<<dim3(NH / 128, NB / 128, 2), blk, 0, stream>>>(latent, W_int, b_int,
                                                                   W_intl, b_intl,
                                                                   i1hi, i1lo, i2hi, i2lo);
    init4<<<dim3(NH / 128, NB / 128, 4), blk, 0, stream>>>(
        i1hi, i1lo, i2hi, i2lo,
        Whp_hi, Whp_lo, Wcp_hi, Wcp_lo, Whlp_hi, Whlp_lo, Wclp_hi, Wclp_lo,
        b_hup, b_cup, b_hupl, b_cupl,
        c1, c2, h1hi[0], h1lo[0], h2hi[0]);
    out1_init<<<dim3(NB * NRW / 256), blk, 0, stream>>>(out1, b_outl);

    const dim3 g1(NG / 128, NB / 128, 1);     // 16 x 64
    const dim3 g2(NG / 128, NB / 128, 2);
    const dim3 gl(4, 128);                    // 64-row logits tiles: 512 blocks

    // ---- t=0 loop-1 gate (x-contribution is zero: inputs == 0) ----
    fused_gate<1, 0><<<g1, blk, 0, stream>>>(h1hi[0], h1lo[0], nullptr,
                                             Wlp_hi, Wlp_lo, blp, gdown, gdownl,
                                             nullptr, out0, 0,
                                             c1, h1hi[1], h1lo[1],
                                             nullptr, nullptr, nullptr, nullptr, 0);
    mfma_logits_argmax<<<gl, blk, 0, stream>>>(h1hi[1], h1lo[1], Wup_hi, Wup_lo,
                                               b_up, gu, part, 0);

    int c1i = 1, c2i = 0;   // current h1 / h2 buffer indices
    for (int t = 0; t < NRW - 1; ++t) {
        const int n1 = c1i ^ 1, n2 = c2i ^ 1;
        fused_gate<1, 1><<<g2, blk, 0, stream>>>(h1hi[c1i], h1lo[c1i], h2hi[c2i],
                                                 Wlp_hi, Wlp_lo, blp, gdown, gdownl,
                                                 part, out0, t,
                                                 c1, h1hi[n1], h1lo[n1],
                                                 c2, h2hi[n2], W_outl, out1, t);
        mfma_logits_argmax<<<gl, blk, 0, stream>>>(h1hi[n1], h1lo[n1], Wup_hi, Wup_lo,
                                                   b_up, gu, part, t + 1);
        c1i = n1;
        c2i = n2;
    }
    // ---- last: loop-2 gate for t=15 + one-hot out0(15) ----
    fused_gate<0, 1><<<g1, blk, 0, stream>>>(nullptr, nullptr, h2hi[c2i],
                                             Wlp_hi, Wlp_lo, blp, gdown, gdownl,
                                             part, out0, NRW - 1,
                                             nullptr, nullptr, nullptr,
                                             c2, h2hi[c2i ^ 1], W_outl, out1, NRW - 1);
}